// Round 12
// baseline (198.923 us; speedup 1.0000x reference)
//
#include <hip/hip_runtime.h>
#include <hip/hip_bf16.h>
#include <math.h>

#define N_NODES 50000
#define N_EDGES 640000
#define IN_DIM 5
#define HID 128
#define NGRAPH 512
#define GEMM_NBLK ((N_NODES + 63) / 64)     // 782
#define EDGE_BLK (N_EDGES / 1024)           // 625 (int4 x 256 threads)
#define TPREP_BLK 32                        // W1 transpose, float4 x 256 threads
#define NROW_BLK ((N_NODES + 255) / 256)    // 196
#define NBIN 128                            // bins by dst>>9; 98 active
#define BIN_SHIFT 9
#define NBIN_ACTIVE ((N_NODES + 511) >> 9)  // 98
#define NSEG 8                              // tail-counter split (hot-atomic chain /8)
#define SEGCAP 1024                         // mean seg load 819, +7 sigma headroom
#define BINCAP (NSEG * SEGCAP)              // 8192

typedef unsigned short u16;
typedef __attribute__((ext_vector_type(8))) short bf16x8;
typedef __attribute__((ext_vector_type(8))) unsigned short u16x8;
typedef __attribute__((ext_vector_type(4))) float f32x4;
typedef __attribute__((ext_vector_type(8))) float f32x8;
// under-aligned float4 for 20B-stride x rows (lowers to one dwordx4 load)
typedef __attribute__((ext_vector_type(4), aligned(4))) float f32x4u;

__device__ __forceinline__ float bf2f(u16 u) {
  union { unsigned int i; float f; } v; v.i = ((unsigned int)u) << 16; return v.f;
}
__device__ __forceinline__ u16 f2bf(float f) {
  return __bfloat16_as_ushort(__float2bfloat16(f));
}

// ---------------- Phase A: LDS-binned edge pass + W1 prep + wvecs + nrow ----------------
// R11 theory: binA's 98 atomics/block on 128 counters = 625-deep serialization chain
// per counter at the coherence point. Split each counter 8 ways (by blockIdx&7) ->
// 78-deep chains. binned gets 8 segments per bin.
__global__ __launch_bounds__(256) void binA_k(const int* __restrict__ src,
                                              const int* __restrict__ dst,
                                              int* __restrict__ bin_tail,
                                              unsigned int* __restrict__ binned,
                                              const float* __restrict__ W1rel,
                                              const float* __restrict__ W1root,
                                              u16* __restrict__ T1rel, u16* __restrict__ T1root,
                                              const float* __restrict__ Wrel2,
                                              const float* __restrict__ Wroot2,
                                              const float* __restrict__ b2,
                                              const float* __restrict__ Wlin,
                                              float* __restrict__ wvecs,
                                              const int* __restrict__ batch,
                                              int* __restrict__ nrow) {
  int b = blockIdx.x;
  int t = threadIdx.x;
  if (b < EDGE_BLK) {
    __shared__ int hist[NBIN];
    __shared__ int scan_s[NBIN];
    __shared__ int gbase[NBIN];
    __shared__ int sc[256];
    __shared__ unsigned int stage[1024];
    __shared__ unsigned char binof[1024];
    const int seg = b & (NSEG - 1);
    for (int i = t; i < NBIN; i += 256) hist[i] = 0;
    __syncthreads();
    int e0 = (b * 256 + t) * 4;
    int4 s4 = *(const int4*)(src + e0);
    int4 d4 = *(const int4*)(dst + e0);
    int ss[4] = {s4.x, s4.y, s4.z, s4.w};
    int dd[4] = {d4.x, d4.y, d4.z, d4.w};
    int mybin[4], myoff[4];
#pragma unroll
    for (int j = 0; j < 4; ++j) {
      mybin[j] = dd[j] >> BIN_SHIFT;
      myoff[j] = atomicAdd(&hist[mybin[j]], 1);   // LDS atomic
    }
    __syncthreads();
    // exclusive scan over NBIN (padded to 256)
    int c = (t < NBIN) ? hist[t] : 0;
    sc[t] = c;
    __syncthreads();
#pragma unroll
    for (int o = 1; o < 256; o <<= 1) {
      int u = (t >= o) ? sc[t - o] : 0;
      __syncthreads();
      sc[t] += u;
      __syncthreads();
    }
    if (t < NBIN) {
      scan_s[t] = sc[t] - c;
      // 8-way-split tail: chain depth per address 625 -> ~78
      gbase[t] = (c > 0) ? atomicAdd(&bin_tail[t * NSEG + seg], c) : 0;
    }
    __syncthreads();
#pragma unroll
    for (int j = 0; j < 4; ++j) {
      int pos = scan_s[mybin[j]] + myoff[j];
      stage[pos] = ((unsigned int)dd[j] << 16) | (unsigned int)ss[j];
      binof[pos] = (unsigned char)mybin[j];
    }
    __syncthreads();
    // bin-sorted write-out: consecutive i -> consecutive addresses within chunks
    for (int i = t; i < 1024; i += 256) {
      int bb = binof[i];
      int pos = gbase[bb] + (i - scan_s[bb]);
      if (pos < SEGCAP)
        binned[(size_t)bb * BINCAP + (size_t)seg * SEGCAP + pos] = stage[i];
    }
  } else if (b < EDGE_BLK + TPREP_BLK) {
    int idx4 = ((b - EDGE_BLK) * 256 + t) * 4;
    int which = idx4 >> 14;                 // HID*HID = 16384
    int i = idx4 & (HID * HID - 1);         // k*128 + n, n%4==0
    const float* W = which == 0 ? W1rel : W1root;
    u16* T = which == 0 ? T1rel : T1root;
    int k = i >> 7, n = i & 127;
    float4 w4 = *(const float4*)(W + i);
    T[(n + 0) * HID + k] = f2bf(w4.x);
    T[(n + 1) * HID + k] = f2bf(w4.y);
    T[(n + 2) * HID + k] = f2bf(w4.z);
    T[(n + 3) * HID + k] = f2bf(w4.w);
  } else if (b == EDGE_BLK + TPREP_BLK) {
    if (t < 128) {
      float s = 0.f;
      for (int c = 0; c < HID; ++c) s = fmaf(Wrel2[t * HID + c], Wlin[c], s);
      wvecs[t] = s;
    } else {
      int k = t - 128;
      float s = 0.f;
      for (int c = 0; c < HID; ++c) s = fmaf(Wroot2[k * HID + c], Wlin[c], s);
      wvecs[128 + k] = s;
    }
    if (t == 0) {
      float s = 0.f;
      for (int c = 0; c < HID; ++c) s = fmaf(b2[c], Wlin[c], s);
      wvecs[256] = s;
    }
  } else {
    // nrow: graph node boundaries from sorted batch (handles empty graphs)
    int n = (b - EDGE_BLK - TPREP_BLK - 1) * 256 + t;
    if (n < N_NODES) {
      int bg = batch[n];
      int bp = (n == 0) ? -1 : batch[n - 1];
      for (int g = bp + 1; g <= bg; ++g) nrow[g] = n;
      if (n == N_NODES - 1) {
        for (int g = bg + 1; g <= NGRAPH; ++g) nrow[g] = N_NODES;
      }
    }
  }
}

// ---------------- Phase B: per-bin dense CSR over 8 segments, LDS hist/scan ----------------
__global__ __launch_bounds__(256) void binB_k(const int* __restrict__ bin_tail,
                                              const unsigned int* __restrict__ binned,
                                              u16* __restrict__ esrc2,
                                              int* __restrict__ row_start,
                                              int* __restrict__ cnt2) {
  __shared__ int hist[512];
  __shared__ int sc[256];
  __shared__ int off_s[512];
  __shared__ int total0_s;
  int b = blockIdx.x;
  int t = threadIdx.x;
  size_t base = (size_t)b * BINCAP;
  int ecnt[NSEG];
#pragma unroll
  for (int s = 0; s < NSEG; ++s) ecnt[s] = min(bin_tail[b * NSEG + s], SEGCAP);
  for (int i = t; i < 512; i += 256) hist[i] = 0;
  __syncthreads();
#pragma unroll
  for (int s = 0; s < NSEG; ++s) {
    for (int e = t; e < ecnt[s]; e += 256) {
      int d = binned[base + (size_t)s * SEGCAP + e] >> 16;
      atomicAdd(&hist[d & 511], 1);
    }
  }
  __syncthreads();
  // exclusive scan over 512 = two 256-halves
  int excl0, excl1, tot0;
  {
    int c = hist[t];
    sc[t] = c; __syncthreads();
#pragma unroll
    for (int o = 1; o < 256; o <<= 1) {
      int u = (t >= o) ? sc[t - o] : 0; __syncthreads();
      sc[t] += u; __syncthreads();
    }
    excl0 = sc[t] - c;
    if (t == 255) total0_s = sc[255];
    __syncthreads();
    tot0 = total0_s;
    __syncthreads();
  }
  {
    int c = hist[256 + t];
    sc[t] = c; __syncthreads();
#pragma unroll
    for (int o = 1; o < 256; o <<= 1) {
      int u = (t >= o) ? sc[t - o] : 0; __syncthreads();
      sc[t] += u; __syncthreads();
    }
    excl1 = sc[t] - c + tot0;
  }
  __syncthreads();
  int n0 = b << BIN_SHIFT;
  off_s[t] = excl0;
  off_s[256 + t] = excl1;
  {
    int n = n0 + t;
    if (n < N_NODES) { row_start[n] = (int)base + excl0; cnt2[n] = hist[t]; }
    n = n0 + 256 + t;
    if (n < N_NODES) { row_start[n] = (int)base + excl1; cnt2[n] = hist[256 + t]; }
  }
  __syncthreads();
  // pass 2: scatter src into dense per-bin CSR (writes within a 16KB window)
#pragma unroll
  for (int s = 0; s < NSEG; ++s) {
    for (int e = t; e < ecnt[s]; e += 256) {
      unsigned int rec = binned[base + (size_t)s * SEGCAP + e];
      int d = (rec >> 16) & 511;
      int pos = atomicAdd(&off_s[d], 1);   // LDS atomic
      esrc2[base + pos] = (u16)(rec & 0xFFFFu);
    }
  }
}

// ---------------- Fused layer-0: CSR x-gather + dense projection + dual MFMA GEMM ----
// R9/R11: coalesced LDS-staged epilogue (scattered 2B stores were ~6us of the 35us).
__global__ __launch_bounds__(256, 3) void proj_gemm_k(const float* __restrict__ x,
                                                      const int* __restrict__ row_start,
                                                      const int* __restrict__ cnt2,
                                                      const u16* __restrict__ esrc2,
                                                      const float* __restrict__ Wrel0,
                                                      const float* __restrict__ Wroot0,
                                                      const float* __restrict__ brel0,
                                                      const u16* __restrict__ WrelT,
                                                      const u16* __restrict__ WrootT,
                                                      const float* __restrict__ bias1,
                                                      u16* __restrict__ Z,
                                                      u16* __restrict__ R) {
  __shared__ u16 As[64][136];
  __shared__ float A5s[64][IN_DIM];
  const int tid = threadIdx.x;
  const int r0 = blockIdx.x * 64;

  // ---- x-aggregation for this block's 64 rows: 4 threads per node ----
  {
    const int li = tid >> 2;     // 0..63 local node
    const int l4 = tid & 3;
    const int node = r0 + li;
    float a[IN_DIM];
#pragma unroll
    for (int k = 0; k < IN_DIM; ++k) a[k] = 0.f;
    if (node < N_NODES) {
      int beg = row_start[node];
      int cn = cnt2[node];
      for (int j = l4; j < cn; j += 4) {
        int s = esrc2[beg + j];
        f32x4u xv = *(const f32x4u*)(x + (size_t)s * IN_DIM);   // 1 dwordx4
        float x4 = x[(size_t)s * IN_DIM + 4];                    // + 1 dword
#pragma unroll
        for (int k = 0; k < 4; ++k) a[k] += xv[k];
        a[4] += x4;
      }
    }
#pragma unroll
    for (int k = 0; k < IN_DIM; ++k) {
      a[k] += __shfl_xor(a[k], 1, 64);
      a[k] += __shfl_xor(a[k], 2, 64);
    }
    if (l4 == 0) {
#pragma unroll
      for (int k = 0; k < IN_DIM; ++k) A5s[li][k] = a[k];
    }
  }
  __syncthreads();

  // ---- dense layer-0: each thread computes 16 rows x 2 cols of relu(conv0) ----
  {
    const int c0 = (tid & 63) * 2;   // column pair
    const int rg = tid >> 6;         // row group (wave id)
    float wr0[IN_DIM], wr1[IN_DIM], wo0[IN_DIM], wo1[IN_DIM];
#pragma unroll
    for (int k = 0; k < IN_DIM; ++k) {
      wr0[k] = Wrel0[k * HID + c0];
      wr1[k] = Wrel0[k * HID + c0 + 1];
      wo0[k] = Wroot0[k * HID + c0];
      wo1[k] = Wroot0[k * HID + c0 + 1];
    }
    const float b0 = brel0[c0], b1 = brel0[c0 + 1];
#pragma unroll
    for (int i = 0; i < 16; ++i) {
      int row = rg * 16 + i;
      int grow = r0 + row;
      float v0 = 0.f, v1 = 0.f;
      if (grow < N_NODES) {
        v0 = b0; v1 = b1;
        f32x4u xv = *(const f32x4u*)(x + (size_t)grow * IN_DIM);
        float x4 = x[(size_t)grow * IN_DIM + 4];
        float xr[IN_DIM] = {xv[0], xv[1], xv[2], xv[3], x4};
#pragma unroll
        for (int k = 0; k < IN_DIM; ++k) {
          float a = A5s[row][k];
          v0 = fmaf(a, wr0[k], fmaf(xr[k], wo0[k], v0));
          v1 = fmaf(a, wr1[k], fmaf(xr[k], wo1[k], v1));
        }
      }
      ushort2 w2;
      w2.x = f2bf(fmaxf(v0, 0.f));
      w2.y = f2bf(fmaxf(v1, 0.f));
      *(ushort2*)&As[row][c0] = w2;
    }
  }
  __syncthreads();

  // ---- MFMA phase (verified layout): wv 0,1 -> Z cols 0..63/64..127; wv 2,3 -> R ----
  const int wv = tid >> 6, lane = tid & 63;
  const int m = lane & 15, quad = lane >> 4;
  const u16* WT = (wv < 2) ? WrelT : WrootT;
  const int n0 = (wv & 1) * 64;

  f32x4 acc[4][4];
#pragma unroll
  for (int mt = 0; mt < 4; ++mt)
#pragma unroll
    for (int nt = 0; nt < 4; ++nt) acc[mt][nt] = (f32x4){0.f, 0.f, 0.f, 0.f};

#pragma unroll
  for (int ks = 0; ks < 4; ++ks) {
    int kb = ks * 32;
    bf16x8 af[4], bf[4];
#pragma unroll
    for (int mt = 0; mt < 4; ++mt)
      af[mt] = *(const bf16x8*)&As[mt * 16 + m][kb + quad * 8];
#pragma unroll
    for (int nt = 0; nt < 4; ++nt)
      bf[nt] = *(const bf16x8*)(WT + (size_t)(n0 + nt * 16 + m) * HID + kb + quad * 8);
#pragma unroll
    for (int mt = 0; mt < 4; ++mt)
#pragma unroll
      for (int nt = 0; nt < 4; ++nt)
        acc[mt][nt] = __builtin_amdgcn_mfma_f32_16x16x32_bf16(af[mt], bf[nt], acc[mt][nt], 0, 0, 0);
  }
  __syncthreads();   // all MFMA reads of As done; tile becomes output staging

  // ---- Z: stage in LDS (2B LDS writes), store coalesced u16x8 (full lines) ----
  if (wv < 2) {
#pragma unroll
    for (int mt = 0; mt < 4; ++mt)
#pragma unroll
      for (int nt = 0; nt < 4; ++nt) {
        int col = n0 + nt * 16 + m;
#pragma unroll
        for (int r = 0; r < 4; ++r)
          As[mt * 16 + quad * 4 + r][col] = f2bf(acc[mt][nt][r]);
      }
  }
  __syncthreads();
#pragma unroll
  for (int it = 0; it < 4; ++it) {
    int idx = it * 256 + tid;
    int row = idx >> 4, qq = idx & 15;
    int grow = r0 + row;
    if (grow < N_NODES)
      *(u16x8*)(Z + (size_t)grow * HID + qq * 8) = *(const u16x8*)&As[row][qq * 8];
  }
  __syncthreads();

  // ---- R: same, with bias ----
  if (wv >= 2) {
    float bl[4];
#pragma unroll
    for (int nt = 0; nt < 4; ++nt) bl[nt] = bias1[n0 + nt * 16 + m];
#pragma unroll
    for (int mt = 0; mt < 4; ++mt)
#pragma unroll
      for (int nt = 0; nt < 4; ++nt) {
        int col = n0 + nt * 16 + m;
#pragma unroll
        for (int r = 0; r < 4; ++r)
          As[mt * 16 + quad * 4 + r][col] = f2bf(acc[mt][nt][r] + bl[nt]);
      }
  }
  __syncthreads();
#pragma unroll
  for (int it = 0; it < 4; ++it) {
    int idx = it * 256 + tid;
    int row = idx >> 4, qq = idx & 15;
    int grow = r0 + row;
    if (grow < N_NODES)
      *(u16x8*)(R + (size_t)grow * HID + qq * 8) = *(const u16x8*)&As[row][qq * 8];
  }
}

// ---- gather helper: unrolled x2, 8 edges in flight per wave (R4-verified form) ----
__device__ __forceinline__ void gather_node(const u16* __restrict__ Z,
                                            const u16* __restrict__ esrc,
                                            int beg, int end, int q, int f8,
                                            f32x8& out) {
  f32x8 a0, a1;
#pragma unroll
  for (int j = 0; j < 8; ++j) { a0[j] = 0.f; a1[j] = 0.f; }
  int e = beg + q;
  for (; e + 4 < end; e += 8) {
    int s0 = esrc[e];
    int s1 = esrc[e + 4];
    u16x8 za = *(const u16x8*)(Z + (size_t)s0 * HID + f8);
    u16x8 zb = *(const u16x8*)(Z + (size_t)s1 * HID + f8);
#pragma unroll
    for (int j = 0; j < 8; ++j) { a0[j] += bf2f(za[j]); a1[j] += bf2f(zb[j]); }
  }
  if (e < end) {
    int s0 = esrc[e];
    u16x8 za = *(const u16x8*)(Z + (size_t)s0 * HID + f8);
#pragma unroll
    for (int j = 0; j < 8; ++j) a0[j] += bf2f(za[j]);
  }
#pragma unroll
  for (int j = 0; j < 8; ++j) out[j] = a0[j] + a1[j];
}

// ---------------- Layer-1 agg + layer-2 scalar collapse (wave per node; ~32us) ----------
__global__ __launch_bounds__(256) void agg_s_k(const u16* __restrict__ Z,
                                               const int* __restrict__ row_start,
                                               const int* __restrict__ cnt2,
                                               const u16* __restrict__ esrc2,
                                               const u16* __restrict__ R,
                                               const float* __restrict__ wvecs,
                                               float* __restrict__ s_rel,
                                               float* __restrict__ s_root) {
  int wave = threadIdx.x >> 6;
  int lane = threadIdx.x & 63;
  int node = blockIdx.x * 4 + wave;
  if (node >= N_NODES) return;
  int q = lane >> 4;
  int l16 = lane & 15;
  int f8 = l16 * 8;
  int beg = row_start[node];
  int end = beg + cnt2[node];
  f32x8 acc;
  gather_node(Z, esrc2, beg, end, q, f8, acc);
#pragma unroll
  for (int j = 0; j < 8; ++j) {
    acc[j] += __shfl_xor(acc[j], 16, 64);
    acc[j] += __shfl_xor(acc[j], 32, 64);
  }
  if (q == 0) {
    const u16* rp = R + (size_t)node * HID + f8;
    u16x8 r8 = *(const u16x8*)rp;
    float sr = 0.f, so = 0.f;
#pragma unroll
    for (int j = 0; j < 8; ++j) {
      float h = fmaxf(bf2f(r8[j]) + acc[j], 0.f);
      sr = fmaf(h, wvecs[f8 + j], sr);
      so = fmaf(h, wvecs[128 + f8 + j], so);
    }
#pragma unroll
    for (int w = 1; w < 16; w <<= 1) {
      sr += __shfl_xor(sr, w, 16);
      so += __shfl_xor(so, w, 16);
    }
    if (l16 == 0) {
      s_rel[node] = sr;
      s_root[node] = so;
    }
  }
}

// ---------------- Block-per-graph pooled reduction + head (NO atomics) ----------------
__global__ __launch_bounds__(256) void pool_final_k(const float* __restrict__ s_rel,
                                                    const float* __restrict__ s_root,
                                                    const int* __restrict__ row_start,
                                                    const int* __restrict__ cnt2,
                                                    const u16* __restrict__ esrc2,
                                                    const int* __restrict__ nrow,
                                                    const float* __restrict__ wvecs,
                                                    const float* __restrict__ blin,
                                                    float* __restrict__ out) {
  int g = blockIdx.x;
  int n0 = nrow[g], n1 = nrow[g + 1];
  int wave = threadIdx.x >> 6;
  int lane = threadIdx.x & 63;
  float s = 0.f;
  for (int n = n0 + wave; n < n1; n += 4) {
    int c = min(cnt2[n], 64);
    if (lane < c) s += s_rel[esrc2[row_start[n] + lane]];
  }
  for (int n = n0 + threadIdx.x; n < n1; n += 256) s += s_root[n];
  __shared__ float red[4];
#pragma unroll
  for (int w = 32; w; w >>= 1) s += __shfl_down(s, w, 64);
  if (lane == 0) red[wave] = s;
  __syncthreads();
  if (threadIdx.x == 0) {
    float t = red[0] + red[1] + red[2] + red[3];
    float cntf = (float)(n1 - n0);
    float cmax = fmaxf(cntf, 1.f);
    float logit = (t + cntf * wvecs[256]) / cmax + blin[0];
    out[g] = 1.f / (1.f + expf(-logit));
  }
}

// ================= host launch =================

extern "C" void kernel_launch(void* const* d_in, const int* in_sizes, int n_in,
                              void* d_out, int out_size, void* d_ws, size_t ws_size,
                              hipStream_t stream) {
  const float* x      = (const float*)d_in[0];
  const int*   ei     = (const int*)d_in[1];
  const int*   batch  = (const int*)d_in[2];
  const float* Wrel0  = (const float*)d_in[3];
  const float* brel0  = (const float*)d_in[4];
  const float* Wroot0 = (const float*)d_in[5];
  const float* Wrel1  = (const float*)d_in[6];
  const float* brel1  = (const float*)d_in[7];
  const float* Wroot1 = (const float*)d_in[8];
  const float* Wrel2  = (const float*)d_in[9];
  const float* brel2  = (const float*)d_in[10];
  const float* Wroot2 = (const float*)d_in[11];
  const float* Wlin   = (const float*)d_in[12];
  const float* blin   = (const float*)d_in[13];
  float* out = (float*)d_out;
  const int* srcp = ei;
  const int* dstp = ei + N_EDGES;

  char* ws = (char*)d_ws;
  size_t off = 0;
  auto alloc = [&](size_t b) { size_t o = off; off += (b + 255) & ~(size_t)255; return (void*)(ws + o); };
  u16*  Z      = (u16*)alloc(sizeof(u16) * N_NODES * HID);
  u16*  R      = (u16*)alloc(sizeof(u16) * N_NODES * HID);
  float* s_rel  = (float*)alloc(sizeof(float) * N_NODES);
  float* s_root = (float*)alloc(sizeof(float) * N_NODES);
  u16* WT1rel  = (u16*)alloc(sizeof(u16) * HID * HID);
  u16* WT1root = (u16*)alloc(sizeof(u16) * HID * HID);
  float* wvecs = (float*)alloc(sizeof(float) * 260);
  int* nrow    = (int*)alloc(sizeof(int) * (NGRAPH + 1));
  unsigned int* binned = (unsigned int*)alloc(sizeof(unsigned int) * (size_t)NBIN * BINCAP); // 4MB
  u16* esrc2   = (u16*)alloc(sizeof(u16) * (size_t)NBIN * BINCAP);                            // 2MB
  int* row_start = (int*)alloc(sizeof(int) * N_NODES);
  int* cnt2      = (int*)alloc(sizeof(int) * N_NODES);
  // zero region: bin_tail (NBIN*NSEG ints = 4KB)
  size_t zero_base = off;
  int* bin_tail = (int*)alloc(sizeof(int) * NBIN * NSEG);
  size_t zero_len = off - zero_base;

  hipMemsetAsync(ws + zero_base, 0, zero_len, stream);

  binA_k<<<EDGE_BLK + TPREP_BLK + 1 + NROW_BLK, 256, 0, stream>>>(
      srcp, dstp, bin_tail, binned, Wrel1, Wroot1, WT1rel, WT1root,
      Wrel2, Wroot2, brel2, Wlin, wvecs, batch, nrow);
  binB_k<<<NBIN_ACTIVE, 256, 0, stream>>>(bin_tail, binned, esrc2, row_start, cnt2);
  proj_gemm_k<<<GEMM_NBLK, 256, 0, stream>>>(x, row_start, cnt2, esrc2,
                                             Wrel0, Wroot0, brel0,
                                             WT1rel, WT1root, brel1, Z, R);
  agg_s_k<<<(N_NODES + 3) / 4, 256, 0, stream>>>(Z, row_start, cnt2, esrc2, R, wvecs,
                                                 s_rel, s_root);
  pool_final_k<<<NGRAPH, 256, 0, stream>>>(s_rel, s_root, row_start, cnt2, esrc2,
                                           nrow, wvecs, blin, out);
}

// Round 13
// 182.546 us; speedup vs baseline: 1.0897x; 1.0897x over previous
//
#include <hip/hip_runtime.h>
#include <hip/hip_bf16.h>
#include <math.h>

#define N_NODES 50000
#define N_EDGES 640000
#define IN_DIM 5
#define HID 128
#define NGRAPH 512
#define GEMM_NBLK ((N_NODES + 63) / 64)     // 782
#define EDGE_BLK (N_EDGES / 1024)           // 625 (int4 x 256 threads)
#define TPREP_BLK 32                        // W1 transpose, float4 x 256 threads
#define NROW_BLK ((N_NODES + 255) / 256)    // 196
#define NBIN 128                            // bins by dst>>9; 98 active
#define BIN_SHIFT 9
#define NBIN_ACTIVE ((N_NODES + 511) >> 9)  // 98
#define BINCAP 8192                         // mean load 6530, max ~6900 << 8192

typedef unsigned short u16;
typedef __attribute__((ext_vector_type(8))) short bf16x8;
typedef __attribute__((ext_vector_type(8))) unsigned short u16x8;
typedef __attribute__((ext_vector_type(4))) float f32x4;
typedef __attribute__((ext_vector_type(8))) float f32x8;
// under-aligned float4 for 20B-stride x rows (lowers to one dwordx4 load)
typedef __attribute__((ext_vector_type(4), aligned(4))) float f32x4u;

__device__ __forceinline__ float bf2f(u16 u) {
  union { unsigned int i; float f; } v; v.i = ((unsigned int)u) << 16; return v.f;
}
__device__ __forceinline__ u16 f2bf(float f) {
  return __bfloat16_as_ushort(__float2bfloat16(f));
}

// ---------------- Phase A: LDS-binned edge pass + W1 prep + wvecs + nrow ----------------
// (R12: 8-way tail-split falsified the hot-atomic theory — reverted to R11 form.)
__global__ __launch_bounds__(256) void binA_k(const int* __restrict__ src,
                                              const int* __restrict__ dst,
                                              int* __restrict__ bin_tail,
                                              unsigned int* __restrict__ binned,
                                              const float* __restrict__ W1rel,
                                              const float* __restrict__ W1root,
                                              u16* __restrict__ T1rel, u16* __restrict__ T1root,
                                              const float* __restrict__ Wrel2,
                                              const float* __restrict__ Wroot2,
                                              const float* __restrict__ b2,
                                              const float* __restrict__ Wlin,
                                              float* __restrict__ wvecs,
                                              const int* __restrict__ batch,
                                              int* __restrict__ nrow) {
  int b = blockIdx.x;
  int t = threadIdx.x;
  if (b < EDGE_BLK) {
    __shared__ int hist[NBIN];
    __shared__ int scan_s[NBIN];
    __shared__ int gbase[NBIN];
    __shared__ int sc[256];
    __shared__ unsigned int stage[1024];
    __shared__ unsigned char binof[1024];
    for (int i = t; i < NBIN; i += 256) hist[i] = 0;
    __syncthreads();
    int e0 = (b * 256 + t) * 4;
    int4 s4 = *(const int4*)(src + e0);
    int4 d4 = *(const int4*)(dst + e0);
    int ss[4] = {s4.x, s4.y, s4.z, s4.w};
    int dd[4] = {d4.x, d4.y, d4.z, d4.w};
    int mybin[4], myoff[4];
#pragma unroll
    for (int j = 0; j < 4; ++j) {
      mybin[j] = dd[j] >> BIN_SHIFT;
      myoff[j] = atomicAdd(&hist[mybin[j]], 1);   // LDS atomic
    }
    __syncthreads();
    // exclusive scan over NBIN (padded to 256)
    int c = (t < NBIN) ? hist[t] : 0;
    sc[t] = c;
    __syncthreads();
#pragma unroll
    for (int o = 1; o < 256; o <<= 1) {
      int u = (t >= o) ? sc[t - o] : 0;
      __syncthreads();
      sc[t] += u;
      __syncthreads();
    }
    if (t < NBIN) {
      scan_s[t] = sc[t] - c;
      gbase[t] = (c > 0) ? atomicAdd(&bin_tail[t], c) : 0;   // 98 global atomics/block
    }
    __syncthreads();
#pragma unroll
    for (int j = 0; j < 4; ++j) {
      int pos = scan_s[mybin[j]] + myoff[j];
      stage[pos] = ((unsigned int)dd[j] << 16) | (unsigned int)ss[j];
      binof[pos] = (unsigned char)mybin[j];
    }
    __syncthreads();
    // bin-sorted write-out: consecutive i -> consecutive addresses within chunks
    for (int i = t; i < 1024; i += 256) {
      int bb = binof[i];
      int pos = gbase[bb] + (i - scan_s[bb]);
      if (pos < BINCAP) binned[(size_t)bb * BINCAP + pos] = stage[i];
    }
  } else if (b < EDGE_BLK + TPREP_BLK) {
    int idx4 = ((b - EDGE_BLK) * 256 + t) * 4;
    int which = idx4 >> 14;                 // HID*HID = 16384
    int i = idx4 & (HID * HID - 1);         // k*128 + n, n%4==0
    const float* W = which == 0 ? W1rel : W1root;
    u16* T = which == 0 ? T1rel : T1root;
    int k = i >> 7, n = i & 127;
    float4 w4 = *(const float4*)(W + i);
    T[(n + 0) * HID + k] = f2bf(w4.x);
    T[(n + 1) * HID + k] = f2bf(w4.y);
    T[(n + 2) * HID + k] = f2bf(w4.z);
    T[(n + 3) * HID + k] = f2bf(w4.w);
  } else if (b == EDGE_BLK + TPREP_BLK) {
    if (t < 128) {
      float s = 0.f;
      for (int c = 0; c < HID; ++c) s = fmaf(Wrel2[t * HID + c], Wlin[c], s);
      wvecs[t] = s;
    } else {
      int k = t - 128;
      float s = 0.f;
      for (int c = 0; c < HID; ++c) s = fmaf(Wroot2[k * HID + c], Wlin[c], s);
      wvecs[128 + k] = s;
    }
    if (t == 0) {
      float s = 0.f;
      for (int c = 0; c < HID; ++c) s = fmaf(b2[c], Wlin[c], s);
      wvecs[256] = s;
    }
  } else {
    // nrow: graph node boundaries from sorted batch (handles empty graphs)
    int n = (b - EDGE_BLK - TPREP_BLK - 1) * 256 + t;
    if (n < N_NODES) {
      int bg = batch[n];
      int bp = (n == 0) ? -1 : batch[n - 1];
      for (int g = bp + 1; g <= bg; ++g) nrow[g] = n;
      if (n == N_NODES - 1) {
        for (int g = bg + 1; g <= NGRAPH; ++g) nrow[g] = N_NODES;
      }
    }
  }
}

// ---------------- Phase B: per-bin dense CSR, all counting/scan in LDS ----------------
__global__ __launch_bounds__(256) void binB_k(const int* __restrict__ bin_tail,
                                              const unsigned int* __restrict__ binned,
                                              u16* __restrict__ esrc2,
                                              int* __restrict__ row_start,
                                              int* __restrict__ cnt2) {
  __shared__ int hist[512];
  __shared__ int sc[256];
  __shared__ int off_s[512];
  __shared__ int total0_s;
  int b = blockIdx.x;
  int t = threadIdx.x;
  int ecnt = min(bin_tail[b], BINCAP);
  size_t base = (size_t)b * BINCAP;
  for (int i = t; i < 512; i += 256) hist[i] = 0;
  __syncthreads();
  for (int e = t; e < ecnt; e += 256) {
    int d = binned[base + e] >> 16;
    atomicAdd(&hist[d & 511], 1);
  }
  __syncthreads();
  // exclusive scan over 512 = two 256-halves
  int excl0, excl1, tot0;
  {
    int c = hist[t];
    sc[t] = c; __syncthreads();
#pragma unroll
    for (int o = 1; o < 256; o <<= 1) {
      int u = (t >= o) ? sc[t - o] : 0; __syncthreads();
      sc[t] += u; __syncthreads();
    }
    excl0 = sc[t] - c;
    if (t == 255) total0_s = sc[255];
    __syncthreads();
    tot0 = total0_s;
    __syncthreads();
  }
  {
    int c = hist[256 + t];
    sc[t] = c; __syncthreads();
#pragma unroll
    for (int o = 1; o < 256; o <<= 1) {
      int u = (t >= o) ? sc[t - o] : 0; __syncthreads();
      sc[t] += u; __syncthreads();
    }
    excl1 = sc[t] - c + tot0;
  }
  __syncthreads();
  int n0 = b << BIN_SHIFT;
  off_s[t] = excl0;
  off_s[256 + t] = excl1;
  {
    int n = n0 + t;
    if (n < N_NODES) { row_start[n] = (int)base + excl0; cnt2[n] = hist[t]; }
    n = n0 + 256 + t;
    if (n < N_NODES) { row_start[n] = (int)base + excl1; cnt2[n] = hist[256 + t]; }
  }
  __syncthreads();
  // pass 2: scatter src into dense per-bin CSR (writes within a 16KB window)
  for (int e = t; e < ecnt; e += 256) {
    unsigned int rec = binned[base + e];
    int d = (rec >> 16) & 511;
    int pos = atomicAdd(&off_s[d], 1);   // LDS atomic
    esrc2[base + pos] = (u16)(rec & 0xFFFFu);
  }
}

// ---------------- Fused layer-0: CSR x-gather + dense projection + dual MFMA GEMM ----
// R9/R11: coalesced LDS-staged epilogue (scattered 2B stores were ~6us of the 35us).
__global__ __launch_bounds__(256, 3) void proj_gemm_k(const float* __restrict__ x,
                                                      const int* __restrict__ row_start,
                                                      const int* __restrict__ cnt2,
                                                      const u16* __restrict__ esrc2,
                                                      const float* __restrict__ Wrel0,
                                                      const float* __restrict__ Wroot0,
                                                      const float* __restrict__ brel0,
                                                      const u16* __restrict__ WrelT,
                                                      const u16* __restrict__ WrootT,
                                                      const float* __restrict__ bias1,
                                                      u16* __restrict__ Z,
                                                      u16* __restrict__ R) {
  __shared__ u16 As[64][136];
  __shared__ float A5s[64][IN_DIM];
  const int tid = threadIdx.x;
  const int r0 = blockIdx.x * 64;

  // ---- x-aggregation for this block's 64 rows: 4 threads per node ----
  {
    const int li = tid >> 2;     // 0..63 local node
    const int l4 = tid & 3;
    const int node = r0 + li;
    float a[IN_DIM];
#pragma unroll
    for (int k = 0; k < IN_DIM; ++k) a[k] = 0.f;
    if (node < N_NODES) {
      int beg = row_start[node];
      int cn = cnt2[node];
      for (int j = l4; j < cn; j += 4) {
        int s = esrc2[beg + j];
        f32x4u xv = *(const f32x4u*)(x + (size_t)s * IN_DIM);   // 1 dwordx4
        float x4 = x[(size_t)s * IN_DIM + 4];                    // + 1 dword
#pragma unroll
        for (int k = 0; k < 4; ++k) a[k] += xv[k];
        a[4] += x4;
      }
    }
#pragma unroll
    for (int k = 0; k < IN_DIM; ++k) {
      a[k] += __shfl_xor(a[k], 1, 64);
      a[k] += __shfl_xor(a[k], 2, 64);
    }
    if (l4 == 0) {
#pragma unroll
      for (int k = 0; k < IN_DIM; ++k) A5s[li][k] = a[k];
    }
  }
  __syncthreads();

  // ---- dense layer-0: each thread computes 16 rows x 2 cols of relu(conv0) ----
  {
    const int c0 = (tid & 63) * 2;   // column pair
    const int rg = tid >> 6;         // row group (wave id)
    float wr0[IN_DIM], wr1[IN_DIM], wo0[IN_DIM], wo1[IN_DIM];
#pragma unroll
    for (int k = 0; k < IN_DIM; ++k) {
      wr0[k] = Wrel0[k * HID + c0];
      wr1[k] = Wrel0[k * HID + c0 + 1];
      wo0[k] = Wroot0[k * HID + c0];
      wo1[k] = Wroot0[k * HID + c0 + 1];
    }
    const float b0 = brel0[c0], b1 = brel0[c0 + 1];
#pragma unroll
    for (int i = 0; i < 16; ++i) {
      int row = rg * 16 + i;
      int grow = r0 + row;
      float v0 = 0.f, v1 = 0.f;
      if (grow < N_NODES) {
        v0 = b0; v1 = b1;
        f32x4u xv = *(const f32x4u*)(x + (size_t)grow * IN_DIM);
        float x4 = x[(size_t)grow * IN_DIM + 4];
        float xr[IN_DIM] = {xv[0], xv[1], xv[2], xv[3], x4};
#pragma unroll
        for (int k = 0; k < IN_DIM; ++k) {
          float a = A5s[row][k];
          v0 = fmaf(a, wr0[k], fmaf(xr[k], wo0[k], v0));
          v1 = fmaf(a, wr1[k], fmaf(xr[k], wo1[k], v1));
        }
      }
      ushort2 w2;
      w2.x = f2bf(fmaxf(v0, 0.f));
      w2.y = f2bf(fmaxf(v1, 0.f));
      *(ushort2*)&As[row][c0] = w2;
    }
  }
  __syncthreads();

  // ---- MFMA phase (verified layout): wv 0,1 -> Z cols 0..63/64..127; wv 2,3 -> R ----
  const int wv = tid >> 6, lane = tid & 63;
  const int m = lane & 15, quad = lane >> 4;
  const u16* WT = (wv < 2) ? WrelT : WrootT;
  const int n0 = (wv & 1) * 64;

  f32x4 acc[4][4];
#pragma unroll
  for (int mt = 0; mt < 4; ++mt)
#pragma unroll
    for (int nt = 0; nt < 4; ++nt) acc[mt][nt] = (f32x4){0.f, 0.f, 0.f, 0.f};

#pragma unroll
  for (int ks = 0; ks < 4; ++ks) {
    int kb = ks * 32;
    bf16x8 af[4], bf[4];
#pragma unroll
    for (int mt = 0; mt < 4; ++mt)
      af[mt] = *(const bf16x8*)&As[mt * 16 + m][kb + quad * 8];
#pragma unroll
    for (int nt = 0; nt < 4; ++nt)
      bf[nt] = *(const bf16x8*)(WT + (size_t)(n0 + nt * 16 + m) * HID + kb + quad * 8);
#pragma unroll
    for (int mt = 0; mt < 4; ++mt)
#pragma unroll
      for (int nt = 0; nt < 4; ++nt)
        acc[mt][nt] = __builtin_amdgcn_mfma_f32_16x16x32_bf16(af[mt], bf[nt], acc[mt][nt], 0, 0, 0);
  }
  __syncthreads();   // all MFMA reads of As done; tile becomes output staging

  // ---- Z: stage in LDS (2B LDS writes), store coalesced u16x8 (full lines) ----
  if (wv < 2) {
#pragma unroll
    for (int mt = 0; mt < 4; ++mt)
#pragma unroll
      for (int nt = 0; nt < 4; ++nt) {
        int col = n0 + nt * 16 + m;
#pragma unroll
        for (int r = 0; r < 4; ++r)
          As[mt * 16 + quad * 4 + r][col] = f2bf(acc[mt][nt][r]);
      }
  }
  __syncthreads();
#pragma unroll
  for (int it = 0; it < 4; ++it) {
    int idx = it * 256 + tid;
    int row = idx >> 4, qq = idx & 15;
    int grow = r0 + row;
    if (grow < N_NODES)
      *(u16x8*)(Z + (size_t)grow * HID + qq * 8) = *(const u16x8*)&As[row][qq * 8];
  }
  __syncthreads();

  // ---- R: same, with bias ----
  if (wv >= 2) {
    float bl[4];
#pragma unroll
    for (int nt = 0; nt < 4; ++nt) bl[nt] = bias1[n0 + nt * 16 + m];
#pragma unroll
    for (int mt = 0; mt < 4; ++mt)
#pragma unroll
      for (int nt = 0; nt < 4; ++nt) {
        int col = n0 + nt * 16 + m;
#pragma unroll
        for (int r = 0; r < 4; ++r)
          As[mt * 16 + quad * 4 + r][col] = f2bf(acc[mt][nt][r] + bl[nt]);
      }
  }
  __syncthreads();
#pragma unroll
  for (int it = 0; it < 4; ++it) {
    int idx = it * 256 + tid;
    int row = idx >> 4, qq = idx & 15;
    int grow = r0 + row;
    if (grow < N_NODES)
      *(u16x8*)(R + (size_t)grow * HID + qq * 8) = *(const u16x8*)&As[row][qq * 8];
  }
}

// ---- gather helper: unrolled x2, 8 edges in flight per wave (R4-verified form) ----
__device__ __forceinline__ void gather_node(const u16* __restrict__ Z,
                                            const u16* __restrict__ esrc,
                                            int beg, int end, int q, int f8,
                                            f32x8& out) {
  f32x8 a0, a1;
#pragma unroll
  for (int j = 0; j < 8; ++j) { a0[j] = 0.f; a1[j] = 0.f; }
  int e = beg + q;
  for (; e + 4 < end; e += 8) {
    int s0 = esrc[e];
    int s1 = esrc[e + 4];
    u16x8 za = *(const u16x8*)(Z + (size_t)s0 * HID + f8);
    u16x8 zb = *(const u16x8*)(Z + (size_t)s1 * HID + f8);
#pragma unroll
    for (int j = 0; j < 8; ++j) { a0[j] += bf2f(za[j]); a1[j] += bf2f(zb[j]); }
  }
  if (e < end) {
    int s0 = esrc[e];
    u16x8 za = *(const u16x8*)(Z + (size_t)s0 * HID + f8);
#pragma unroll
    for (int j = 0; j < 8; ++j) a0[j] += bf2f(za[j]);
  }
#pragma unroll
  for (int j = 0; j < 8; ++j) out[j] = a0[j] + a1[j];
}

// ---------------- Layer-1 agg + layer-2 scalar collapse (wave per node; ~32us) ----------
__global__ __launch_bounds__(256) void agg_s_k(const u16* __restrict__ Z,
                                               const int* __restrict__ row_start,
                                               const int* __restrict__ cnt2,
                                               const u16* __restrict__ esrc2,
                                               const u16* __restrict__ R,
                                               const float* __restrict__ wvecs,
                                               float* __restrict__ s_rel,
                                               float* __restrict__ s_root) {
  int wave = threadIdx.x >> 6;
  int lane = threadIdx.x & 63;
  int node = blockIdx.x * 4 + wave;
  if (node >= N_NODES) return;
  int q = lane >> 4;
  int l16 = lane & 15;
  int f8 = l16 * 8;
  int beg = row_start[node];
  int end = beg + cnt2[node];
  f32x8 acc;
  gather_node(Z, esrc2, beg, end, q, f8, acc);
#pragma unroll
  for (int j = 0; j < 8; ++j) {
    acc[j] += __shfl_xor(acc[j], 16, 64);
    acc[j] += __shfl_xor(acc[j], 32, 64);
  }
  if (q == 0) {
    const u16* rp = R + (size_t)node * HID + f8;
    u16x8 r8 = *(const u16x8*)rp;
    float sr = 0.f, so = 0.f;
#pragma unroll
    for (int j = 0; j < 8; ++j) {
      float h = fmaxf(bf2f(r8[j]) + acc[j], 0.f);
      sr = fmaf(h, wvecs[f8 + j], sr);
      so = fmaf(h, wvecs[128 + f8 + j], so);
    }
#pragma unroll
    for (int w = 1; w < 16; w <<= 1) {
      sr += __shfl_xor(sr, w, 16);
      so += __shfl_xor(so, w, 16);
    }
    if (l16 == 0) {
      s_rel[node] = sr;
      s_root[node] = so;
    }
  }
}

// ---------------- Block-per-graph pooled reduction + head, FLAT-SPAN edge iteration ----
// R13: old form had `if(lane<deg)` -> 80% idle lanes (mean deg 12.8 vs 64 lanes).
// batch sorted => graph nodes contiguous; within a bin, node ranges are packed
// (row_start[n+1] = row_start[n]+cnt2[n]) => graph edges = <=bins-touched contiguous
// spans of esrc2. Iterate spans with ALL 256 threads, coalesced index reads.
__global__ __launch_bounds__(256) void pool_final_k(const float* __restrict__ s_rel,
                                                    const float* __restrict__ s_root,
                                                    const int* __restrict__ row_start,
                                                    const int* __restrict__ cnt2,
                                                    const u16* __restrict__ esrc2,
                                                    const int* __restrict__ nrow,
                                                    const float* __restrict__ wvecs,
                                                    const float* __restrict__ blin,
                                                    float* __restrict__ out) {
  int g = blockIdx.x;
  int n0 = nrow[g], n1 = nrow[g + 1];
  int t = threadIdx.x;
  float s = 0.f;
  if (n1 > n0) {
    int b0 = n0 >> BIN_SHIFT, b1 = (n1 - 1) >> BIN_SHIFT;
    for (int b = b0; b <= b1; ++b) {
      int lo = max(n0, b << BIN_SHIFT);
      int hi = min(n1, (b + 1) << BIN_SHIFT);
      int e0 = row_start[lo];
      int e1 = row_start[hi - 1] + cnt2[hi - 1];
      for (int e = e0 + t; e < e1; e += 256) s += s_rel[esrc2[e]];
    }
    for (int n = n0 + t; n < n1; n += 256) s += s_root[n];
  }
  __shared__ float red[4];
#pragma unroll
  for (int w = 32; w; w >>= 1) s += __shfl_down(s, w, 64);
  if ((t & 63) == 0) red[t >> 6] = s;
  __syncthreads();
  if (t == 0) {
    float tt = red[0] + red[1] + red[2] + red[3];
    float cntf = (float)(n1 - n0);
    float cmax = fmaxf(cntf, 1.f);
    float logit = (tt + cntf * wvecs[256]) / cmax + blin[0];
    out[g] = 1.f / (1.f + expf(-logit));
  }
}

// ================= host launch =================

extern "C" void kernel_launch(void* const* d_in, const int* in_sizes, int n_in,
                              void* d_out, int out_size, void* d_ws, size_t ws_size,
                              hipStream_t stream) {
  const float* x      = (const float*)d_in[0];
  const int*   ei     = (const int*)d_in[1];
  const int*   batch  = (const int*)d_in[2];
  const float* Wrel0  = (const float*)d_in[3];
  const float* brel0  = (const float*)d_in[4];
  const float* Wroot0 = (const float*)d_in[5];
  const float* Wrel1  = (const float*)d_in[6];
  const float* brel1  = (const float*)d_in[7];
  const float* Wroot1 = (const float*)d_in[8];
  const float* Wrel2  = (const float*)d_in[9];
  const float* brel2  = (const float*)d_in[10];
  const float* Wroot2 = (const float*)d_in[11];
  const float* Wlin   = (const float*)d_in[12];
  const float* blin   = (const float*)d_in[13];
  float* out = (float*)d_out;
  const int* srcp = ei;
  const int* dstp = ei + N_EDGES;

  char* ws = (char*)d_ws;
  size_t off = 0;
  auto alloc = [&](size_t b) { size_t o = off; off += (b + 255) & ~(size_t)255; return (void*)(ws + o); };
  u16*  Z      = (u16*)alloc(sizeof(u16) * N_NODES * HID);
  u16*  R      = (u16*)alloc(sizeof(u16) * N_NODES * HID);
  float* s_rel  = (float*)alloc(sizeof(float) * N_NODES);
  float* s_root = (float*)alloc(sizeof(float) * N_NODES);
  u16* WT1rel  = (u16*)alloc(sizeof(u16) * HID * HID);
  u16* WT1root = (u16*)alloc(sizeof(u16) * HID * HID);
  float* wvecs = (float*)alloc(sizeof(float) * 260);
  int* nrow    = (int*)alloc(sizeof(int) * (NGRAPH + 1));
  unsigned int* binned = (unsigned int*)alloc(sizeof(unsigned int) * (size_t)NBIN * BINCAP); // 4MB
  u16* esrc2   = (u16*)alloc(sizeof(u16) * (size_t)NBIN * BINCAP);                            // 2MB
  int* row_start = (int*)alloc(sizeof(int) * N_NODES);
  int* cnt2      = (int*)alloc(sizeof(int) * N_NODES);
  // zero region: bin_tail only (512B)
  size_t zero_base = off;
  int* bin_tail = (int*)alloc(sizeof(int) * NBIN);
  size_t zero_len = off - zero_base;

  hipMemsetAsync(ws + zero_base, 0, zero_len, stream);

  binA_k<<<EDGE_BLK + TPREP_BLK + 1 + NROW_BLK, 256, 0, stream>>>(
      srcp, dstp, bin_tail, binned, Wrel1, Wroot1, WT1rel, WT1root,
      Wrel2, Wroot2, brel2, Wlin, wvecs, batch, nrow);
  binB_k<<<NBIN_ACTIVE, 256, 0, stream>>>(bin_tail, binned, esrc2, row_start, cnt2);
  proj_gemm_k<<<GEMM_NBLK, 256, 0, stream>>>(x, row_start, cnt2, esrc2,
                                             Wrel0, Wroot0, brel0,
                                             WT1rel, WT1root, brel1, Z, R);
  agg_s_k<<<(N_NODES + 3) / 4, 256, 0, stream>>>(Z, row_start, cnt2, esrc2, R, wvecs,
                                                 s_rel, s_root);
  pool_final_k<<<NGRAPH, 256, 0, stream>>>(s_rel, s_root, row_start, cnt2, esrc2,
                                           nrow, wvecs, blin, out);
}

// Round 14
// 176.042 us; speedup vs baseline: 1.1300x; 1.0369x over previous
//
#include <hip/hip_runtime.h>
#include <hip/hip_bf16.h>
#include <math.h>

#define N_NODES 50000
#define N_EDGES 640000
#define IN_DIM 5
#define HID 128
#define NGRAPH 512
#define GEMM_NBLK ((N_NODES + 63) / 64)     // 782
#define EDGE_BLK (N_EDGES / 1024)           // 625 (int4 x 256 threads)
#define TPREP_BLK 32                        // W1 transpose, float4 x 256 threads
#define NROW_BLK ((N_NODES + 255) / 256)    // 196
#define NBIN 256                            // bins by dst>>8 (R14: was 128/>>9)
#define BIN_SHIFT 8
#define NBIN_ACTIVE ((N_NODES + 255) >> 8)  // 196 -> 2x binB blocks, half the serial iters
#define BINCAP 4096                         // mean 3277, sigma 57 -> +14 sigma headroom

typedef unsigned short u16;
typedef __attribute__((ext_vector_type(8))) short bf16x8;
typedef __attribute__((ext_vector_type(8))) unsigned short u16x8;
typedef __attribute__((ext_vector_type(4))) float f32x4;
typedef __attribute__((ext_vector_type(8))) float f32x8;
// under-aligned float4 for 20B-stride x rows (lowers to one dwordx4 load)
typedef __attribute__((ext_vector_type(4), aligned(4))) float f32x4u;

__device__ __forceinline__ float bf2f(u16 u) {
  union { unsigned int i; float f; } v; v.i = ((unsigned int)u) << 16; return v.f;
}
__device__ __forceinline__ u16 f2bf(float f) {
  return __bfloat16_as_ushort(__float2bfloat16(f));
}

// ---------------- Phase A: LDS-binned edge pass + W1 prep + wvecs + nrow ----------------
// R14: 256 bins -> exact 256-wide hist/scan (no padding guard).
__global__ __launch_bounds__(256) void binA_k(const int* __restrict__ src,
                                              const int* __restrict__ dst,
                                              int* __restrict__ bin_tail,
                                              unsigned int* __restrict__ binned,
                                              const float* __restrict__ W1rel,
                                              const float* __restrict__ W1root,
                                              u16* __restrict__ T1rel, u16* __restrict__ T1root,
                                              const float* __restrict__ Wrel2,
                                              const float* __restrict__ Wroot2,
                                              const float* __restrict__ b2,
                                              const float* __restrict__ Wlin,
                                              float* __restrict__ wvecs,
                                              const int* __restrict__ batch,
                                              int* __restrict__ nrow) {
  int b = blockIdx.x;
  int t = threadIdx.x;
  if (b < EDGE_BLK) {
    __shared__ int hist[NBIN];
    __shared__ int scan_s[NBIN];
    __shared__ int gbase[NBIN];
    __shared__ int sc[256];
    __shared__ unsigned int stage[1024];
    __shared__ unsigned char binof[1024];
    hist[t] = 0;
    __syncthreads();
    int e0 = (b * 256 + t) * 4;
    int4 s4 = *(const int4*)(src + e0);
    int4 d4 = *(const int4*)(dst + e0);
    int ss[4] = {s4.x, s4.y, s4.z, s4.w};
    int dd[4] = {d4.x, d4.y, d4.z, d4.w};
    int mybin[4], myoff[4];
#pragma unroll
    for (int j = 0; j < 4; ++j) {
      mybin[j] = dd[j] >> BIN_SHIFT;
      myoff[j] = atomicAdd(&hist[mybin[j]], 1);   // LDS atomic
    }
    __syncthreads();
    // exclusive scan over 256 bins (exact width)
    int c = hist[t];
    sc[t] = c;
    __syncthreads();
#pragma unroll
    for (int o = 1; o < 256; o <<= 1) {
      int u = (t >= o) ? sc[t - o] : 0;
      __syncthreads();
      sc[t] += u;
      __syncthreads();
    }
    scan_s[t] = sc[t] - c;
    gbase[t] = (c > 0) ? atomicAdd(&bin_tail[t], c) : 0;   // <=196 global atomics/block
    __syncthreads();
#pragma unroll
    for (int j = 0; j < 4; ++j) {
      int pos = scan_s[mybin[j]] + myoff[j];
      stage[pos] = ((unsigned int)dd[j] << 16) | (unsigned int)ss[j];
      binof[pos] = (unsigned char)mybin[j];
    }
    __syncthreads();
    // bin-sorted write-out: consecutive i -> consecutive addresses within chunks
    for (int i = t; i < 1024; i += 256) {
      int bb = binof[i];
      int pos = gbase[bb] + (i - scan_s[bb]);
      if (pos < BINCAP) binned[(size_t)bb * BINCAP + pos] = stage[i];
    }
  } else if (b < EDGE_BLK + TPREP_BLK) {
    int idx4 = ((b - EDGE_BLK) * 256 + t) * 4;
    int which = idx4 >> 14;                 // HID*HID = 16384
    int i = idx4 & (HID * HID - 1);         // k*128 + n, n%4==0
    const float* W = which == 0 ? W1rel : W1root;
    u16* T = which == 0 ? T1rel : T1root;
    int k = i >> 7, n = i & 127;
    float4 w4 = *(const float4*)(W + i);
    T[(n + 0) * HID + k] = f2bf(w4.x);
    T[(n + 1) * HID + k] = f2bf(w4.y);
    T[(n + 2) * HID + k] = f2bf(w4.z);
    T[(n + 3) * HID + k] = f2bf(w4.w);
  } else if (b == EDGE_BLK + TPREP_BLK) {
    if (t < 128) {
      float s = 0.f;
      for (int c = 0; c < HID; ++c) s = fmaf(Wrel2[t * HID + c], Wlin[c], s);
      wvecs[t] = s;
    } else {
      int k = t - 128;
      float s = 0.f;
      for (int c = 0; c < HID; ++c) s = fmaf(Wroot2[k * HID + c], Wlin[c], s);
      wvecs[128 + k] = s;
    }
    if (t == 0) {
      float s = 0.f;
      for (int c = 0; c < HID; ++c) s = fmaf(b2[c], Wlin[c], s);
      wvecs[256] = s;
    }
  } else {
    // nrow: graph node boundaries from sorted batch (handles empty graphs)
    int n = (b - EDGE_BLK - TPREP_BLK - 1) * 256 + t;
    if (n < N_NODES) {
      int bg = batch[n];
      int bp = (n == 0) ? -1 : batch[n - 1];
      for (int g = bp + 1; g <= bg; ++g) nrow[g] = n;
      if (n == N_NODES - 1) {
        for (int g = bg + 1; g <= NGRAPH; ++g) nrow[g] = N_NODES;
      }
    }
  }
}

// ---------------- Phase B: per-bin dense CSR, single 256-scan (R14: bins=256 nodes) ----
__global__ __launch_bounds__(256) void binB_k(const int* __restrict__ bin_tail,
                                              const unsigned int* __restrict__ binned,
                                              u16* __restrict__ esrc2,
                                              int* __restrict__ row_start,
                                              int* __restrict__ cnt2) {
  __shared__ int hist[256];
  __shared__ int sc[256];
  __shared__ int off_s[256];
  int b = blockIdx.x;
  int t = threadIdx.x;
  int ecnt = min(bin_tail[b], BINCAP);
  size_t base = (size_t)b * BINCAP;
  hist[t] = 0;
  __syncthreads();
  for (int e = t; e < ecnt; e += 256) {
    int d = binned[base + e] >> 16;
    atomicAdd(&hist[d & 255], 1);
  }
  __syncthreads();
  int c = hist[t];
  sc[t] = c;
  __syncthreads();
#pragma unroll
  for (int o = 1; o < 256; o <<= 1) {
    int u = (t >= o) ? sc[t - o] : 0;
    __syncthreads();
    sc[t] += u;
    __syncthreads();
  }
  int excl = sc[t] - c;
  off_s[t] = excl;
  int n = (b << BIN_SHIFT) + t;
  if (n < N_NODES) { row_start[n] = (int)base + excl; cnt2[n] = c; }
  __syncthreads();
  // pass 2: scatter src into dense per-bin CSR (writes within an 8KB window)
  for (int e = t; e < ecnt; e += 256) {
    unsigned int rec = binned[base + e];
    int d = (rec >> 16) & 255;
    int pos = atomicAdd(&off_s[d], 1);   // LDS atomic
    esrc2[base + pos] = (u16)(rec & 0xFFFFu);
  }
}

// ---------------- Fused layer-0: CSR x-gather + dense projection + dual MFMA GEMM ----
// R9/R11: coalesced LDS-staged epilogue (scattered 2B stores were ~6us of the 35us).
__global__ __launch_bounds__(256, 3) void proj_gemm_k(const float* __restrict__ x,
                                                      const int* __restrict__ row_start,
                                                      const int* __restrict__ cnt2,
                                                      const u16* __restrict__ esrc2,
                                                      const float* __restrict__ Wrel0,
                                                      const float* __restrict__ Wroot0,
                                                      const float* __restrict__ brel0,
                                                      const u16* __restrict__ WrelT,
                                                      const u16* __restrict__ WrootT,
                                                      const float* __restrict__ bias1,
                                                      u16* __restrict__ Z,
                                                      u16* __restrict__ R) {
  __shared__ u16 As[64][136];
  __shared__ float A5s[64][IN_DIM];
  const int tid = threadIdx.x;
  const int r0 = blockIdx.x * 64;

  // ---- x-aggregation for this block's 64 rows: 4 threads per node ----
  {
    const int li = tid >> 2;     // 0..63 local node
    const int l4 = tid & 3;
    const int node = r0 + li;
    float a[IN_DIM];
#pragma unroll
    for (int k = 0; k < IN_DIM; ++k) a[k] = 0.f;
    if (node < N_NODES) {
      int beg = row_start[node];
      int cn = cnt2[node];
      for (int j = l4; j < cn; j += 4) {
        int s = esrc2[beg + j];
        f32x4u xv = *(const f32x4u*)(x + (size_t)s * IN_DIM);   // 1 dwordx4
        float x4 = x[(size_t)s * IN_DIM + 4];                    // + 1 dword
#pragma unroll
        for (int k = 0; k < 4; ++k) a[k] += xv[k];
        a[4] += x4;
      }
    }
#pragma unroll
    for (int k = 0; k < IN_DIM; ++k) {
      a[k] += __shfl_xor(a[k], 1, 64);
      a[k] += __shfl_xor(a[k], 2, 64);
    }
    if (l4 == 0) {
#pragma unroll
      for (int k = 0; k < IN_DIM; ++k) A5s[li][k] = a[k];
    }
  }
  __syncthreads();

  // ---- dense layer-0: each thread computes 16 rows x 2 cols of relu(conv0) ----
  {
    const int c0 = (tid & 63) * 2;   // column pair
    const int rg = tid >> 6;         // row group (wave id)
    float wr0[IN_DIM], wr1[IN_DIM], wo0[IN_DIM], wo1[IN_DIM];
#pragma unroll
    for (int k = 0; k < IN_DIM; ++k) {
      wr0[k] = Wrel0[k * HID + c0];
      wr1[k] = Wrel0[k * HID + c0 + 1];
      wo0[k] = Wroot0[k * HID + c0];
      wo1[k] = Wroot0[k * HID + c0 + 1];
    }
    const float b0 = brel0[c0], b1 = brel0[c0 + 1];
#pragma unroll
    for (int i = 0; i < 16; ++i) {
      int row = rg * 16 + i;
      int grow = r0 + row;
      float v0 = 0.f, v1 = 0.f;
      if (grow < N_NODES) {
        v0 = b0; v1 = b1;
        f32x4u xv = *(const f32x4u*)(x + (size_t)grow * IN_DIM);
        float x4 = x[(size_t)grow * IN_DIM + 4];
        float xr[IN_DIM] = {xv[0], xv[1], xv[2], xv[3], x4};
#pragma unroll
        for (int k = 0; k < IN_DIM; ++k) {
          float a = A5s[row][k];
          v0 = fmaf(a, wr0[k], fmaf(xr[k], wo0[k], v0));
          v1 = fmaf(a, wr1[k], fmaf(xr[k], wo1[k], v1));
        }
      }
      ushort2 w2;
      w2.x = f2bf(fmaxf(v0, 0.f));
      w2.y = f2bf(fmaxf(v1, 0.f));
      *(ushort2*)&As[row][c0] = w2;
    }
  }
  __syncthreads();

  // ---- MFMA phase (verified layout): wv 0,1 -> Z cols 0..63/64..127; wv 2,3 -> R ----
  const int wv = tid >> 6, lane = tid & 63;
  const int m = lane & 15, quad = lane >> 4;
  const u16* WT = (wv < 2) ? WrelT : WrootT;
  const int n0 = (wv & 1) * 64;

  f32x4 acc[4][4];
#pragma unroll
  for (int mt = 0; mt < 4; ++mt)
#pragma unroll
    for (int nt = 0; nt < 4; ++nt) acc[mt][nt] = (f32x4){0.f, 0.f, 0.f, 0.f};

#pragma unroll
  for (int ks = 0; ks < 4; ++ks) {
    int kb = ks * 32;
    bf16x8 af[4], bf[4];
#pragma unroll
    for (int mt = 0; mt < 4; ++mt)
      af[mt] = *(const bf16x8*)&As[mt * 16 + m][kb + quad * 8];
#pragma unroll
    for (int nt = 0; nt < 4; ++nt)
      bf[nt] = *(const bf16x8*)(WT + (size_t)(n0 + nt * 16 + m) * HID + kb + quad * 8);
#pragma unroll
    for (int mt = 0; mt < 4; ++mt)
#pragma unroll
      for (int nt = 0; nt < 4; ++nt)
        acc[mt][nt] = __builtin_amdgcn_mfma_f32_16x16x32_bf16(af[mt], bf[nt], acc[mt][nt], 0, 0, 0);
  }
  __syncthreads();   // all MFMA reads of As done; tile becomes output staging

  // ---- Z: stage in LDS (2B LDS writes), store coalesced u16x8 (full lines) ----
  if (wv < 2) {
#pragma unroll
    for (int mt = 0; mt < 4; ++mt)
#pragma unroll
      for (int nt = 0; nt < 4; ++nt) {
        int col = n0 + nt * 16 + m;
#pragma unroll
        for (int r = 0; r < 4; ++r)
          As[mt * 16 + quad * 4 + r][col] = f2bf(acc[mt][nt][r]);
      }
  }
  __syncthreads();
#pragma unroll
  for (int it = 0; it < 4; ++it) {
    int idx = it * 256 + tid;
    int row = idx >> 4, qq = idx & 15;
    int grow = r0 + row;
    if (grow < N_NODES)
      *(u16x8*)(Z + (size_t)grow * HID + qq * 8) = *(const u16x8*)&As[row][qq * 8];
  }
  __syncthreads();

  // ---- R: same, with bias ----
  if (wv >= 2) {
    float bl[4];
#pragma unroll
    for (int nt = 0; nt < 4; ++nt) bl[nt] = bias1[n0 + nt * 16 + m];
#pragma unroll
    for (int mt = 0; mt < 4; ++mt)
#pragma unroll
      for (int nt = 0; nt < 4; ++nt) {
        int col = n0 + nt * 16 + m;
#pragma unroll
        for (int r = 0; r < 4; ++r)
          As[mt * 16 + quad * 4 + r][col] = f2bf(acc[mt][nt][r] + bl[nt]);
      }
  }
  __syncthreads();
#pragma unroll
  for (int it = 0; it < 4; ++it) {
    int idx = it * 256 + tid;
    int row = idx >> 4, qq = idx & 15;
    int grow = r0 + row;
    if (grow < N_NODES)
      *(u16x8*)(R + (size_t)grow * HID + qq * 8) = *(const u16x8*)&As[row][qq * 8];
  }
}

// ---- gather helper: unrolled x2, 8 edges in flight per wave (R4-verified form) ----
__device__ __forceinline__ void gather_node(const u16* __restrict__ Z,
                                            const u16* __restrict__ esrc,
                                            int beg, int end, int q, int f8,
                                            f32x8& out) {
  f32x8 a0, a1;
#pragma unroll
  for (int j = 0; j < 8; ++j) { a0[j] = 0.f; a1[j] = 0.f; }
  int e = beg + q;
  for (; e + 4 < end; e += 8) {
    int s0 = esrc[e];
    int s1 = esrc[e + 4];
    u16x8 za = *(const u16x8*)(Z + (size_t)s0 * HID + f8);
    u16x8 zb = *(const u16x8*)(Z + (size_t)s1 * HID + f8);
#pragma unroll
    for (int j = 0; j < 8; ++j) { a0[j] += bf2f(za[j]); a1[j] += bf2f(zb[j]); }
  }
  if (e < end) {
    int s0 = esrc[e];
    u16x8 za = *(const u16x8*)(Z + (size_t)s0 * HID + f8);
#pragma unroll
    for (int j = 0; j < 8; ++j) a0[j] += bf2f(za[j]);
  }
#pragma unroll
  for (int j = 0; j < 8; ++j) out[j] = a0[j] + a1[j];
}

// ---------------- Layer-1 agg + layer-2 scalar collapse (wave per node; ~32us) ----------
__global__ __launch_bounds__(256) void agg_s_k(const u16* __restrict__ Z,
                                               const int* __restrict__ row_start,
                                               const int* __restrict__ cnt2,
                                               const u16* __restrict__ esrc2,
                                               const u16* __restrict__ R,
                                               const float* __restrict__ wvecs,
                                               float* __restrict__ s_rel,
                                               float* __restrict__ s_root) {
  int wave = threadIdx.x >> 6;
  int lane = threadIdx.x & 63;
  int node = blockIdx.x * 4 + wave;
  if (node >= N_NODES) return;
  int q = lane >> 4;
  int l16 = lane & 15;
  int f8 = l16 * 8;
  int beg = row_start[node];
  int end = beg + cnt2[node];
  f32x8 acc;
  gather_node(Z, esrc2, beg, end, q, f8, acc);
#pragma unroll
  for (int j = 0; j < 8; ++j) {
    acc[j] += __shfl_xor(acc[j], 16, 64);
    acc[j] += __shfl_xor(acc[j], 32, 64);
  }
  if (q == 0) {
    const u16* rp = R + (size_t)node * HID + f8;
    u16x8 r8 = *(const u16x8*)rp;
    float sr = 0.f, so = 0.f;
#pragma unroll
    for (int j = 0; j < 8; ++j) {
      float h = fmaxf(bf2f(r8[j]) + acc[j], 0.f);
      sr = fmaf(h, wvecs[f8 + j], sr);
      so = fmaf(h, wvecs[128 + f8 + j], so);
    }
#pragma unroll
    for (int w = 1; w < 16; w <<= 1) {
      sr += __shfl_xor(sr, w, 16);
      so += __shfl_xor(so, w, 16);
    }
    if (l16 == 0) {
      s_rel[node] = sr;
      s_root[node] = so;
    }
  }
}

// ---------------- Block-per-graph pooled reduction + head, FLAT-SPAN edge iteration ----
// R13 win (+14us): batch sorted => graph edges = few contiguous esrc2 spans; iterate
// edge-parallel with ALL 256 threads (old `if(lane<deg)` left 80% lanes idle).
__global__ __launch_bounds__(256) void pool_final_k(const float* __restrict__ s_rel,
                                                    const float* __restrict__ s_root,
                                                    const int* __restrict__ row_start,
                                                    const int* __restrict__ cnt2,
                                                    const u16* __restrict__ esrc2,
                                                    const int* __restrict__ nrow,
                                                    const float* __restrict__ wvecs,
                                                    const float* __restrict__ blin,
                                                    float* __restrict__ out) {
  int g = blockIdx.x;
  int n0 = nrow[g], n1 = nrow[g + 1];
  int t = threadIdx.x;
  float s = 0.f;
  if (n1 > n0) {
    int b0 = n0 >> BIN_SHIFT, b1 = (n1 - 1) >> BIN_SHIFT;
    for (int b = b0; b <= b1; ++b) {
      int lo = max(n0, b << BIN_SHIFT);
      int hi = min(n1, (b + 1) << BIN_SHIFT);
      int e0 = row_start[lo];
      int e1 = row_start[hi - 1] + cnt2[hi - 1];
      for (int e = e0 + t; e < e1; e += 256) s += s_rel[esrc2[e]];
    }
    for (int n = n0 + t; n < n1; n += 256) s += s_root[n];
  }
  __shared__ float red[4];
#pragma unroll
  for (int w = 32; w; w >>= 1) s += __shfl_down(s, w, 64);
  if ((t & 63) == 0) red[t >> 6] = s;
  __syncthreads();
  if (t == 0) {
    float tt = red[0] + red[1] + red[2] + red[3];
    float cntf = (float)(n1 - n0);
    float cmax = fmaxf(cntf, 1.f);
    float logit = (tt + cntf * wvecs[256]) / cmax + blin[0];
    out[g] = 1.f / (1.f + expf(-logit));
  }
}

// ================= host launch =================

extern "C" void kernel_launch(void* const* d_in, const int* in_sizes, int n_in,
                              void* d_out, int out_size, void* d_ws, size_t ws_size,
                              hipStream_t stream) {
  const float* x      = (const float*)d_in[0];
  const int*   ei     = (const int*)d_in[1];
  const int*   batch  = (const int*)d_in[2];
  const float* Wrel0  = (const float*)d_in[3];
  const float* brel0  = (const float*)d_in[4];
  const float* Wroot0 = (const float*)d_in[5];
  const float* Wrel1  = (const float*)d_in[6];
  const float* brel1  = (const float*)d_in[7];
  const float* Wroot1 = (const float*)d_in[8];
  const float* Wrel2  = (const float*)d_in[9];
  const float* brel2  = (const float*)d_in[10];
  const float* Wroot2 = (const float*)d_in[11];
  const float* Wlin   = (const float*)d_in[12];
  const float* blin   = (const float*)d_in[13];
  float* out = (float*)d_out;
  const int* srcp = ei;
  const int* dstp = ei + N_EDGES;

  char* ws = (char*)d_ws;
  size_t off = 0;
  auto alloc = [&](size_t b) { size_t o = off; off += (b + 255) & ~(size_t)255; return (void*)(ws + o); };
  u16*  Z      = (u16*)alloc(sizeof(u16) * N_NODES * HID);
  u16*  R      = (u16*)alloc(sizeof(u16) * N_NODES * HID);
  float* s_rel  = (float*)alloc(sizeof(float) * N_NODES);
  float* s_root = (float*)alloc(sizeof(float) * N_NODES);
  u16* WT1rel  = (u16*)alloc(sizeof(u16) * HID * HID);
  u16* WT1root = (u16*)alloc(sizeof(u16) * HID * HID);
  float* wvecs = (float*)alloc(sizeof(float) * 260);
  int* nrow    = (int*)alloc(sizeof(int) * (NGRAPH + 1));
  unsigned int* binned = (unsigned int*)alloc(sizeof(unsigned int) * (size_t)NBIN * BINCAP); // 4MB
  u16* esrc2   = (u16*)alloc(sizeof(u16) * (size_t)NBIN * BINCAP);                            // 2MB
  int* row_start = (int*)alloc(sizeof(int) * N_NODES);
  int* cnt2      = (int*)alloc(sizeof(int) * N_NODES);
  // zero region: bin_tail only (1KB)
  size_t zero_base = off;
  int* bin_tail = (int*)alloc(sizeof(int) * NBIN);
  size_t zero_len = off - zero_base;

  hipMemsetAsync(ws + zero_base, 0, zero_len, stream);

  binA_k<<<EDGE_BLK + TPREP_BLK + 1 + NROW_BLK, 256, 0, stream>>>(
      srcp, dstp, bin_tail, binned, Wrel1, Wroot1, WT1rel, WT1root,
      Wrel2, Wroot2, brel2, Wlin, wvecs, batch, nrow);
  binB_k<<<NBIN_ACTIVE, 256, 0, stream>>>(bin_tail, binned, esrc2, row_start, cnt2);
  proj_gemm_k<<<GEMM_NBLK, 256, 0, stream>>>(x, row_start, cnt2, esrc2,
                                             Wrel0, Wroot0, brel0,
                                             WT1rel, WT1root, brel1, Z, R);
  agg_s_k<<<(N_NODES + 3) / 4, 256, 0, stream>>>(Z, row_start, cnt2, esrc2, R, wvecs,
                                                 s_rel, s_root);
  pool_final_k<<<NGRAPH, 256, 0, stream>>>(s_rel, s_root, row_start, cnt2, esrc2,
                                           nrow, wvecs, blin, out);
}